// Round 12
// baseline (315.951 us; speedup 1.0000x reference)
//
#include <hip/hip_runtime.h>
#include <hip/hip_bf16.h>
#include <stdint.h>

#define NN 50000
#define EE 800000
#define DD 128
#define LL 3
#define FILL_CHUNKS 98  // blocks per XCD-range; grid = 8*98

typedef __attribute__((ext_vector_type(8))) short short8;
typedef __attribute__((ext_vector_type(4))) float float4v;

__device__ __forceinline__ float bf2f(unsigned int u) {
  union { unsigned int i; float f; } x; x.i = u << 16; return x.f;
}
__device__ __forceinline__ unsigned short f2bf(float f) {
  union { float f; unsigned int i; } x; x.f = f;
  unsigned int r = x.i + 0x7FFFu + ((x.i >> 16) & 1u);
  return (unsigned short)(r >> 16);
}

// ---------------- CSR build ----------------
__global__ void deg_kernel(const int* __restrict__ dst, int* __restrict__ deg, int E) {
  int e = blockIdx.x * blockDim.x + threadIdx.x;
  if (e < E) atomicAdd(&deg[__builtin_nontemporal_load(dst + e)], 1);
}

// 3-phase parallel exclusive scan.
__global__ __launch_bounds__(256) void scan1_kernel(
    const int* __restrict__ deg, int* __restrict__ incl, int* __restrict__ partial, int N) {
  __shared__ int wsums[4];
  const int tid = threadIdx.x, lane = tid & 63, wid = tid >> 6;
  int i = blockIdx.x * 256 + tid;
  int v = (i < N) ? deg[i] : 0;
  int x = v;
#pragma unroll
  for (int off = 1; off < 64; off <<= 1) {
    int y = __shfl_up(x, off, 64);
    if (lane >= off) x += y;
  }
  if (lane == 63) wsums[wid] = x;
  __syncthreads();
  if (tid == 0) {
    int a0 = wsums[0], a1 = wsums[1], a2 = wsums[2];
    wsums[0] = 0; wsums[1] = a0; wsums[2] = a0 + a1; wsums[3] = a0 + a1 + a2;
  }
  __syncthreads();
  int inc = wsums[wid] + x;
  if (i < N) incl[i] = inc;
  if (tid == 255) partial[blockIdx.x] = inc;
}

__global__ __launch_bounds__(256) void scan2_kernel(int* __restrict__ partial, int P) {
  __shared__ int wsums[4];
  const int tid = threadIdx.x, lane = tid & 63, wid = tid >> 6;
  int v = (tid < P) ? partial[tid] : 0;
  int x = v;
#pragma unroll
  for (int off = 1; off < 64; off <<= 1) {
    int y = __shfl_up(x, off, 64);
    if (lane >= off) x += y;
  }
  if (lane == 63) wsums[wid] = x;
  __syncthreads();
  if (tid == 0) {
    int a0 = wsums[0], a1 = wsums[1], a2 = wsums[2];
    wsums[0] = 0; wsums[1] = a0; wsums[2] = a0 + a1; wsums[3] = a0 + a1 + a2;
  }
  __syncthreads();
  int excl = wsums[wid] + x - v;
  if (tid < P) partial[tid] = excl;
}

__global__ __launch_bounds__(256) void scan3_kernel(
    const int* __restrict__ incl, const int* __restrict__ deg, const int* __restrict__ partial,
    int* __restrict__ rowptr, int* __restrict__ cursor, int N) {
  int i = blockIdx.x * 256 + threadIdx.x;
  if (i < N) {
    int rp = incl[i] - deg[i] + partial[blockIdx.x];
    rowptr[i] = rp;
    cursor[i] = rp;
  }
  if (i == 0) rowptr[N] = EE;
}

// XCD-partitioned CSR fill. Round-12 fix: the dst/src scans are NON-TEMPORAL so the 51 MB
// of redundant streaming reads stop evicting the XCD-local col/cursor lines from L2 —
// round 11 showed the partition alone leaves WRITE_SIZE at 31 MB because the streams
// thrash the 400 KB of col residency they were meant to protect.
__global__ __launch_bounds__(256) void fill_kernel(
    const int* __restrict__ src, const int* __restrict__ dst,
    int* __restrict__ cursor, int* __restrict__ col, int E) {
  const int range = blockIdx.x & 7;
  const int chunk = blockIdx.x >> 3;
  const int lo = range * (NN / 8);
  const int hi = lo + (NN / 8);
  const int per = (E + FILL_CHUNKS - 1) / FILL_CHUNKS;
  const int e0 = chunk * per;
  const int e1 = (e0 + per < E) ? (e0 + per) : E;
  for (int e = e0 + threadIdx.x; e < e1; e += 256) {
    int d = __builtin_nontemporal_load(dst + e);
    if (d >= lo && d < hi) {
      int sv = __builtin_nontemporal_load(src + e);
      int pos = atomicAdd(&cursor[d], 1);
      col[pos] = sv;
    }
  }
}

// ---------------- fp32 -> bf16 (x) ----------------
__global__ void convert_kernel(const float* __restrict__ x, unsigned short* __restrict__ hbf, int n4) {
  int i = blockIdx.x * blockDim.x + threadIdx.x;
  if (i < n4) {
    float4 v = ((const float4*)x)[i];
    ushort4 o;
    o.x = f2bf(v.x); o.y = f2bf(v.y); o.z = f2bf(v.z); o.w = f2bf(v.w);
    ((ushort4*)hbf)[i] = o;
  }
}

// ---------------- weight repack into MFMA B-fragment order (bf16) ----------------
// B[k][n]: k<128 -> Wl[l][n][k]; k>=128 -> Wr[l][n][k-128]
// layout [l][ks][t][lane][j]: n = t*16 + (lane&15), k = ks*32 + (lane>>4)*8 + j
__global__ void repack_kernel(const float* __restrict__ Wl, const float* __restrict__ Wr,
                              unsigned short* __restrict__ out) {
  int tid = blockIdx.x * blockDim.x + threadIdx.x;
  if (tid >= LL * 8 * 8 * 64) return;
  int lane = tid & 63;
  int t = (tid >> 6) & 7;
  int ks = (tid >> 9) & 7;
  int l = tid >> 12;
  int n = t * 16 + (lane & 15);
  int kbase = ks * 32 + (lane >> 4) * 8;
  const float* Wsrc = (ks < 4) ? (Wl + ((size_t)(l * 128 + n) * 128 + kbase))
                               : (Wr + ((size_t)(l * 128 + n) * 128 + (kbase - 128)));
#pragma unroll
  for (int j = 0; j < 8; j++) out[(size_t)tid * 8 + j] = f2bf(Wsrc[j]);
}

// ---------------- CSR pull mean-aggregation (bf16 gather, fp32 accum, bf16 out) ----------
__global__ __launch_bounds__(256) void agg_kernel(
    const unsigned short* __restrict__ hbf, const int* __restrict__ rowptr,
    const int* __restrict__ col, unsigned short* __restrict__ agg, int N) {
  int node = blockIdx.x * 4 + (threadIdx.x >> 6);
  if (node >= N) return;
  int lane = threadIdx.x & 63;
  int s = rowptr[node], e = rowptr[node + 1];
  float ax = 0.f, ay = 0.f;
  int i = s;
  for (; i + 15 < e; i += 16) {
    int idx[16];
#pragma unroll
    for (int j = 0; j < 16; j++) idx[j] = col[i + j];
    unsigned int r[16];
#pragma unroll
    for (int j = 0; j < 16; j++) r[j] = ((const unsigned int*)(hbf + (size_t)idx[j] * 128))[lane];
#pragma unroll
    for (int j = 0; j < 16; j++) {
      ax += bf2f(r[j] & 0xffffu);
      ay += bf2f(r[j] >> 16);
    }
  }
  if (i + 7 < e) {
    int idx[8];
#pragma unroll
    for (int j = 0; j < 8; j++) idx[j] = col[i + j];
    unsigned int r[8];
#pragma unroll
    for (int j = 0; j < 8; j++) r[j] = ((const unsigned int*)(hbf + (size_t)idx[j] * 128))[lane];
#pragma unroll
    for (int j = 0; j < 8; j++) {
      ax += bf2f(r[j] & 0xffffu);
      ay += bf2f(r[j] >> 16);
    }
    i += 8;
  }
  if (i + 3 < e) {
    int idx[4];
#pragma unroll
    for (int j = 0; j < 4; j++) idx[j] = col[i + j];
    unsigned int r[4];
#pragma unroll
    for (int j = 0; j < 4; j++) r[j] = ((const unsigned int*)(hbf + (size_t)idx[j] * 128))[lane];
#pragma unroll
    for (int j = 0; j < 4; j++) {
      ax += bf2f(r[j] & 0xffffu);
      ay += bf2f(r[j] >> 16);
    }
    i += 4;
  }
  for (; i < e; i++) {
    unsigned int r0 = ((const unsigned int*)(hbf + (size_t)col[i] * 128))[lane];
    ax += bf2f(r0 & 0xffffu);
    ay += bf2f(r0 >> 16);
  }
  int dg = e - s;
  float inv = 1.0f / (float)(dg > 1 ? dg : 1);
  ax *= inv; ay *= inv;
  ((unsigned int*)(agg + (size_t)node * 128))[lane] =
      ((unsigned int)f2bf(ay) << 16) | (unsigned int)f2bf(ax);
}

// ---------------- plain-bf16 MFMA GEMM + bias + LDS-epilogue LayerNorm + ReLU ----------------
// MFMA core + LDS-LN epilogue HW-validated (round-7 probe); plain-bf16 inputs validated
// round 10 (absmax 0.0234).
template <bool LAST>
__global__ __launch_bounds__(256) void gemm_ln_mfma_kernel(
    const unsigned short* __restrict__ agg, const unsigned short* __restrict__ h,
    const unsigned short* __restrict__ Bf, const float* __restrict__ bias,
    const float* __restrict__ gamma, const float* __restrict__ beta,
    unsigned short* __restrict__ out_bf, float* __restrict__ f_out, int N) {
  __shared__ unsigned short Bl[8 * 8 * 512];  // 64 KB
  __shared__ float reds[64][16];
  __shared__ float redss[64][16];
  __shared__ float mu_s[64], rs_s[64];
  const int tid = threadIdx.x;
  {
    const uint4* srcB = (const uint4*)Bf;
    uint4* dstB = (uint4*)Bl;
#pragma unroll
    for (int i = 0; i < 16; i++) dstB[tid + i * 256] = srcB[tid + i * 256];
  }
  __syncthreads();
  const int wave = tid >> 6, lane = tid & 63;
  const int ln16 = lane & 15, quad = lane >> 4;
  const int m0 = blockIdx.x * 64 + wave * 16;
  int row_a = m0 + ln16;
  if (row_a > N - 1) row_a = N - 1;  // clamp: MFMA rows independent; stores guarded below
  const size_t aoff = (size_t)row_a * 128 + quad * 8;

  float4v acc[8];
#pragma unroll
  for (int t = 0; t < 8; t++) acc[t] = (float4v)0.f;

#pragma unroll
  for (int ks = 0; ks < 8; ks++) {
    const unsigned short* ap = (ks < 4) ? (agg + aoff + ks * 32) : (h + aoff + (ks - 4) * 32);
    short8 a = *(const short8*)ap;
#pragma unroll
    for (int t = 0; t < 8; t++) {
      short8 b = *(const short8*)&Bl[(ks * 8 + t) * 512 + lane * 8];
      acc[t] = __builtin_amdgcn_mfma_f32_16x16x32_bf16(a, b, acc[t], 0, 0, 0);
    }
  }

  float bias_v[8], g_v[8], b_v[8];
#pragma unroll
  for (int t = 0; t < 8; t++) {
    int c = t * 16 + ln16;
    bias_v[t] = bias[c]; g_v[t] = gamma[c]; b_v[t] = beta[c];
  }
  // LDS-based LN statistics (no cross-lane shuffles — shfl-16 epilogue was the old bug)
#pragma unroll
  for (int r = 0; r < 4; r++) {
    float s = 0.f, ss = 0.f;
#pragma unroll
    for (int t = 0; t < 8; t++) {
      float val = acc[t][r] + bias_v[t];
      s += val; ss += val * val;
    }
    int rowblk = wave * 16 + quad * 4 + r;
    reds[rowblk][ln16] = s;
    redss[rowblk][ln16] = ss;
  }
  __syncthreads();
  if (tid < 64) {
    float s = 0.f, ss = 0.f;
#pragma unroll
    for (int g = 0; g < 16; g++) { s += reds[tid][g]; ss += redss[tid][g]; }
    float mu = s * (1.0f / 128.0f);
    float var = ss * (1.0f / 128.0f) - mu * mu;
    if (var < 0.f) var = 0.f;
    mu_s[tid] = mu;
    rs_s[tid] = rsqrtf(var + 1e-5f);
  }
  __syncthreads();
#pragma unroll
  for (int r = 0; r < 4; r++) {
    int row = m0 + quad * 4 + r;
    int rowblk = wave * 16 + quad * 4 + r;
    if (row < N) {
      float mu = mu_s[rowblk], rs = rs_s[rowblk];
#pragma unroll
      for (int t = 0; t < 8; t++) {
        float val = acc[t][r] + bias_v[t];
        float y = (val - mu) * rs * g_v[t] + b_v[t];
        y = y > 0.f ? y : 0.f;
        int cidx = t * 16 + ln16;
        if (LAST) {
          f_out[(size_t)row * 128 + cidx] = y;
        } else {
          out_bf[(size_t)row * 128 + cidx] = f2bf(y);
        }
      }
    }
  }
}

extern "C" void kernel_launch(void* const* d_in, const int* in_sizes, int n_in,
                              void* d_out, int out_size, void* d_ws, size_t ws_size,
                              hipStream_t stream) {
  const float* x = (const float*)d_in[0];
  const int* edge = (const int*)d_in[1];
  const float* Wl = (const float*)d_in[2];
  const float* bl = (const float*)d_in[3];
  const float* Wr = (const float*)d_in[4];
  const float* gamma = (const float*)d_in[5];
  const float* beta = (const float*)d_in[6];
  float* out = (float*)d_out;

  const int* srcv = edge;       // edge_index[0]
  const int* dstv = edge + EE;  // edge_index[1]

  char* p = (char*)d_ws;
  auto alloc = [&](size_t bytes) {
    char* r = p;
    p += (bytes + 255) & ~(size_t)255;
    return r;
  };
  const size_t bplane = (size_t)NN * 128 * 2;  // 12.8 MB bf16 plane
  unsigned short* xB = (unsigned short*)alloc(bplane);
  unsigned short* h1B = (unsigned short*)alloc(bplane);
  unsigned short* h2B = (unsigned short*)alloc(bplane);
  unsigned short* agB = (unsigned short*)alloc(bplane);
  unsigned short* BfB = (unsigned short*)alloc((size_t)LL * 32768 * 2);
  int* deg = (int*)alloc((size_t)NN * 4);
  int* incl = (int*)alloc((size_t)NN * 4);
  int* cursor = (int*)alloc((size_t)NN * 4);
  int* rowptr = (int*)alloc((size_t)(NN + 1) * 4);
  int* colarr = (int*)alloc((size_t)EE * 4);
  int* partial = (int*)alloc((size_t)256 * 4);
  if ((size_t)(p - (char*)d_ws) > ws_size) return;

  const int SCAN_BLOCKS = (NN + 255) / 256;  // 196

  hipMemsetAsync(deg, 0, (size_t)NN * 4, stream);
  deg_kernel<<<(EE + 255) / 256, 256, 0, stream>>>(dstv, deg, EE);
  scan1_kernel<<<SCAN_BLOCKS, 256, 0, stream>>>(deg, incl, partial, NN);
  scan2_kernel<<<1, 256, 0, stream>>>(partial, SCAN_BLOCKS);
  scan3_kernel<<<SCAN_BLOCKS, 256, 0, stream>>>(incl, deg, partial, rowptr, cursor, NN);
  fill_kernel<<<8 * FILL_CHUNKS, 256, 0, stream>>>(srcv, dstv, cursor, colarr, EE);
  convert_kernel<<<(NN * 128 / 4 + 255) / 256, 256, 0, stream>>>(x, xB, NN * 128 / 4);
  repack_kernel<<<(LL * 4096 + 255) / 256, 256, 0, stream>>>(Wl, Wr, BfB);

  const int gemm_grid = (NN + 63) / 64;
  const int agg_grid = (NN + 3) / 4;

  // ---- layer 0 ----
  agg_kernel<<<agg_grid, 256, 0, stream>>>(xB, rowptr, colarr, agB, NN);
  gemm_ln_mfma_kernel<false><<<gemm_grid, 256, 0, stream>>>(
      agB, xB, BfB, bl, gamma, beta, h1B, nullptr, NN);

  // ---- layer 1 ----
  agg_kernel<<<agg_grid, 256, 0, stream>>>(h1B, rowptr, colarr, agB, NN);
  gemm_ln_mfma_kernel<false><<<gemm_grid, 256, 0, stream>>>(
      agB, h1B, BfB + 32768, bl + 128, gamma + 128, beta + 128, h2B, nullptr, NN);

  // ---- layer 2 ----
  agg_kernel<<<agg_grid, 256, 0, stream>>>(h2B, rowptr, colarr, agB, NN);
  gemm_ln_mfma_kernel<true><<<gemm_grid, 256, 0, stream>>>(
      agB, h2B, BfB + 2 * 32768, bl + 256, gamma + 256, beta + 256, nullptr, out, NN);
}